// Round 3
// baseline (3385.373 us; speedup 1.0000x reference)
//
#include <hip/hip_runtime.h>
#include <math.h>

// Shapes (fixed by the reference):
//   query:  (8, 1024, 1024) f32
//   input:  (8, 4096, 1024) f32
//   mask:   (8, 4096) bool -> harness materializes as int32
//   Wq,Wk,Wo: (1024,1024) f32; bq,bk,bo: (1024,) f32
//   out:    (8, 1024, 1024) f32
//
// Algebra: scores = Q''·input^T + const(q),  Q'' = query·(Wq^T·Wk) + bq·Wk
// (bk contributes only per-row constants -> cancels in softmax).

#define TILE 64
#define KT 16

// C[M][N] = A_eff[M][K] * B_eff[K][N] (+ bias[N])
//  AT=false: A stored [M][lda] ; AT=true: A stored [K][lda], A_eff[i][k]=A[k*lda+i]
//  BT=false: B stored [K][ldb] ; BT=true: B stored [N][ldb], B_eff[k][j]=B[j*ldb+k]
// All dims must be multiples of 64 (M,N) and 16 (K) -- true for every call here.
template<bool AT, bool BT>
__global__ __launch_bounds__(256)
void gemm_k(const float* __restrict__ A, const float* __restrict__ B,
            const float* __restrict__ bias, float* __restrict__ C,
            int M, int N, int K, int lda, int ldb, int ldc)
{
    __shared__ float As[KT][TILE];
    __shared__ float Bs[KT][TILE];
    const int t  = threadIdx.x;
    const int tx = t & 15, ty = t >> 4;
    const int i0 = blockIdx.y * TILE;
    const int j0 = blockIdx.x * TILE;

    float acc[4][4] = {};

    for (int k0 = 0; k0 < K; k0 += KT) {
        if constexpr (!AT) {
            const int ii = t >> 2, kc = t & 3;
            const float4 v = *reinterpret_cast<const float4*>(
                &A[(size_t)(i0 + ii) * lda + k0 + kc * 4]);
            As[kc*4+0][ii] = v.x; As[kc*4+1][ii] = v.y;
            As[kc*4+2][ii] = v.z; As[kc*4+3][ii] = v.w;
        } else {
            const int kk = t >> 4, j4 = t & 15;
            *reinterpret_cast<float4*>(&As[kk][j4*4]) =
                *reinterpret_cast<const float4*>(
                    &A[(size_t)(k0 + kk) * lda + i0 + j4 * 4]);
        }
        if constexpr (!BT) {
            const int kk = t >> 4, j4 = t & 15;
            *reinterpret_cast<float4*>(&Bs[kk][j4*4]) =
                *reinterpret_cast<const float4*>(
                    &B[(size_t)(k0 + kk) * ldb + j0 + j4 * 4]);
        } else {
            const int jj = t >> 2, kc = t & 3;
            const float4 v = *reinterpret_cast<const float4*>(
                &B[(size_t)(j0 + jj) * ldb + k0 + kc * 4]);
            Bs[kc*4+0][jj] = v.x; Bs[kc*4+1][jj] = v.y;
            Bs[kc*4+2][jj] = v.z; Bs[kc*4+3][jj] = v.w;
        }
        __syncthreads();
        #pragma unroll
        for (int kk = 0; kk < KT; ++kk) {
            const float4 a = *reinterpret_cast<const float4*>(&As[kk][ty*4]);
            const float4 b = *reinterpret_cast<const float4*>(&Bs[kk][tx*4]);
            const float a4[4] = {a.x, a.y, a.z, a.w};
            const float b4[4] = {b.x, b.y, b.z, b.w};
            #pragma unroll
            for (int i = 0; i < 4; ++i)
                #pragma unroll
                for (int j = 0; j < 4; ++j)
                    acc[i][j] = fmaf(a4[i], b4[j], acc[i][j]);
        }
        __syncthreads();
    }

    float4 bv = make_float4(0.f, 0.f, 0.f, 0.f);
    if (bias) bv = *reinterpret_cast<const float4*>(&bias[j0 + tx*4]);
    #pragma unroll
    for (int r = 0; r < 4; ++r) {
        float4 o;
        o.x = acc[r][0] + bv.x; o.y = acc[r][1] + bv.y;
        o.z = acc[r][2] + bv.z; o.w = acc[r][3] + bv.w;
        *reinterpret_cast<float4*>(
            &C[(size_t)(i0 + ty*4 + r) * ldc + j0 + tx*4]) = o;
    }
}

// b'[j] = sum_d bq[d] * Wk[d][j]   (tiny; bq happens to be zeros but stay general)
__global__ __launch_bounds__(256)
void bias_proj_k(const float* __restrict__ bq, const float* __restrict__ Wk,
                 float* __restrict__ bp)
{
    const int j = blockIdx.x * 256 + threadIdx.x;
    float s = 0.f;
    for (int d = 0; d < 1024; ++d) s = fmaf(bq[d], Wk[d * 1024 + j], s);
    bp[j] = s;
}

// In-place masked softmax over rows of length 4096. mask int32 != 0 -> -inf.
__global__ __launch_bounds__(256)
void softmax_rows_k(float* __restrict__ S, const int* __restrict__ mask)
{
    const int t = threadIdx.x;
    float* srow = S + (size_t)blockIdx.x * 4096;

    float4 v[4];
    float lmax = -INFINITY;
    #pragma unroll
    for (int c = 0; c < 4; ++c) {
        const int idx = c * 1024 + t * 4;
        v[c] = *reinterpret_cast<const float4*>(&srow[idx]);
        const int4 m4 = *reinterpret_cast<const int4*>(&mask[idx]);
        if (m4.x) v[c].x = -INFINITY;
        if (m4.y) v[c].y = -INFINITY;
        if (m4.z) v[c].z = -INFINITY;
        if (m4.w) v[c].w = -INFINITY;
        lmax = fmaxf(lmax, fmaxf(fmaxf(v[c].x, v[c].y), fmaxf(v[c].z, v[c].w)));
    }
    #pragma unroll
    for (int off = 32; off > 0; off >>= 1)
        lmax = fmaxf(lmax, __shfl_xor(lmax, off));

    __shared__ float redm[4], reds[4];
    if ((t & 63) == 0) redm[t >> 6] = lmax;
    __syncthreads();
    const float bmax = fmaxf(fmaxf(redm[0], redm[1]), fmaxf(redm[2], redm[3]));

    float lsum = 0.f;
    #pragma unroll
    for (int c = 0; c < 4; ++c) {
        v[c].x = __expf(v[c].x - bmax);
        v[c].y = __expf(v[c].y - bmax);
        v[c].z = __expf(v[c].z - bmax);
        v[c].w = __expf(v[c].w - bmax);
        lsum += (v[c].x + v[c].y) + (v[c].z + v[c].w);
    }
    #pragma unroll
    for (int off = 32; off > 0; off >>= 1)
        lsum += __shfl_xor(lsum, off);
    if ((t & 63) == 0) reds[t >> 6] = lsum;
    __syncthreads();
    const float Z = (reds[0] + reds[1]) + (reds[2] + reds[3]);
    const float inv = 1.0f / Z;

    #pragma unroll
    for (int c = 0; c < 4; ++c) {
        const int idx = c * 1024 + t * 4;
        float4 o;
        o.x = v[c].x * inv; o.y = v[c].y * inv;
        o.z = v[c].z * inv; o.w = v[c].w * inv;
        *reinterpret_cast<float4*>(&srow[idx]) = o;
    }
}

extern "C" void kernel_launch(void* const* d_in, const int* in_sizes, int n_in,
                              void* d_out, int out_size, void* d_ws, size_t ws_size,
                              hipStream_t stream)
{
    (void)in_sizes; (void)n_in; (void)out_size; (void)ws_size;
    const int NB = 8, LQ = 1024, LI = 4096, D = 1024;

    const float* query = (const float*)d_in[0];
    const float* input = (const float*)d_in[1];
    const int* mask = (const int*)d_in[2];   // bool -> int32 on device
    const float* Wq = (const float*)d_in[3];
    const float* bq = (const float*)d_in[4];
    const float* Wk = (const float*)d_in[5];
    /* d_in[6] = bk: provably cancels in softmax (per-row constant) */
    const float* Wo = (const float*)d_in[7];
    const float* bo = (const float*)d_in[8];
    float* out = (float*)d_out;

    // ws layout (floats): W'[D*D] | b'[D] | Q''[NB*LQ*D] | S[LQ*LI] | O[NB*LQ*D]
    float* Wp  = (float*)d_ws;
    float* bp  = Wp + (size_t)D * D;
    float* Qpp = bp + D;
    float* S   = Qpp + (size_t)NB * LQ * D;
    float* O   = S + (size_t)LQ * LI;
    // total ~ 84 MB

    dim3 blk(256);

    // W' = Wq^T @ Wk  (A transposed)
    gemm_k<true, false><<<dim3(D/64, D/64), blk, 0, stream>>>(
        Wq, Wk, nullptr, Wp, D, D, D, D, D, D);
    // b' = bq @ Wk
    bias_proj_k<<<dim3(D/256), blk, 0, stream>>>(bq, Wk, bp);
    // Q'' = query @ W' + b'
    gemm_k<false, false><<<dim3(D/64, (NB*LQ)/64), blk, 0, stream>>>(
        query, Wp, bp, Qpp, NB*LQ, D, D, D, D, D);

    for (int n = 0; n < NB; ++n) {
        const float* inp_n = input + (size_t)n * LI * D;
        // S = Q''_n @ input_n^T   (B transposed)
        gemm_k<false, true><<<dim3(LI/64, LQ/64), blk, 0, stream>>>(
            Qpp + (size_t)n * LQ * D, inp_n, nullptr, S, LQ, LI, D, D, D, LI);
        // masked softmax rows, in place
        softmax_rows_k<<<dim3(LQ), blk, 0, stream>>>(S, mask + (size_t)n * LI);
        // O_n = P @ input_n
        gemm_k<false, false><<<dim3(D/64, LQ/64), blk, 0, stream>>>(
            S, inp_n, nullptr, O + (size_t)n * LQ * D, LQ, D, LI, LI, D, D);
    }

    // out = O @ Wo^T + bo  (B transposed)
    gemm_k<false, true><<<dim3(D/64, (NB*LQ)/64), blk, 0, stream>>>(
        O, Wo, bo, out, NB*LQ, D, D, D, D, D);
}

// Round 5
// 938.407 us; speedup vs baseline: 3.6076x; 3.6076x over previous
//
#include <hip/hip_runtime.h>
#include <hip/hip_bf16.h>
#include <math.h>

// CrossAttention (N=8, Lq=1024, Lk=4096, D=1024), fp32 in/out.
// Algebra: scores = Q''*input^T (+row const) ; Q'' = query*(Wq^T*Wk) + bq*Wk ;
// bk cancels in softmax. V = unprojected input. out = (P*V)*Wo^T + bo.
// Precision: split-bf16 (hi+lo, 3-MFMA) on the score path; plain bf16 on PV/out-proj.

using short8 = __attribute__((ext_vector_type(8))) short;
using f32x4  = __attribute__((ext_vector_type(4))) float;

__device__ inline ushort f2bf_u(float f) {
    __hip_bfloat16 b = __float2bfloat16(f);
    return __builtin_bit_cast(ushort, b);
}
__device__ inline float bfu2f(ushort u) {
    __hip_bfloat16 b = __builtin_bit_cast(__hip_bfloat16, u);
    return __bfloat162float(b);
}
__device__ inline void split2(float x, ushort& h, ushort& l) {
    const ushort hu = f2bf_u(x);
    h = hu;
    l = f2bf_u(x - bfu2f(hu));
}

// ---------------------------------------------------------------------------
// fp32 fallback GEMM (R3, proven correct) — used if ws_size too small.
// ---------------------------------------------------------------------------
#define TILE 64
#define KT 16
template<bool AT, bool BT>
__global__ __launch_bounds__(256)
void gemm_k(const float* __restrict__ A, const float* __restrict__ B,
            const float* __restrict__ bias, float* __restrict__ C,
            int M, int N, int K, int lda, int ldb, int ldc)
{
    __shared__ float As[KT][TILE];
    __shared__ float Bs[KT][TILE];
    const int t  = threadIdx.x;
    const int tx = t & 15, ty = t >> 4;
    const int i0 = blockIdx.y * TILE;
    const int j0 = blockIdx.x * TILE;
    float acc[4][4] = {};
    for (int k0 = 0; k0 < K; k0 += KT) {
        if constexpr (!AT) {
            const int ii = t >> 2, kc = t & 3;
            const float4 v = *reinterpret_cast<const float4*>(
                &A[(size_t)(i0 + ii) * lda + k0 + kc * 4]);
            As[kc*4+0][ii] = v.x; As[kc*4+1][ii] = v.y;
            As[kc*4+2][ii] = v.z; As[kc*4+3][ii] = v.w;
        } else {
            const int kk = t >> 4, j4 = t & 15;
            *reinterpret_cast<float4*>(&As[kk][j4*4]) =
                *reinterpret_cast<const float4*>(
                    &A[(size_t)(k0 + kk) * lda + i0 + j4 * 4]);
        }
        if constexpr (!BT) {
            const int kk = t >> 4, j4 = t & 15;
            *reinterpret_cast<float4*>(&Bs[kk][j4*4]) =
                *reinterpret_cast<const float4*>(
                    &B[(size_t)(k0 + kk) * ldb + j0 + j4 * 4]);
        } else {
            const int jj = t >> 2, kc = t & 3;
            const float4 v = *reinterpret_cast<const float4*>(
                &B[(size_t)(j0 + jj) * ldb + k0 + kc * 4]);
            Bs[kc*4+0][jj] = v.x; Bs[kc*4+1][jj] = v.y;
            Bs[kc*4+2][jj] = v.z; Bs[kc*4+3][jj] = v.w;
        }
        __syncthreads();
        #pragma unroll
        for (int kk = 0; kk < KT; ++kk) {
            const float4 a = *reinterpret_cast<const float4*>(&As[kk][ty*4]);
            const float4 b = *reinterpret_cast<const float4*>(&Bs[kk][tx*4]);
            const float a4[4] = {a.x, a.y, a.z, a.w};
            const float b4[4] = {b.x, b.y, b.z, b.w};
            #pragma unroll
            for (int i = 0; i < 4; ++i)
                #pragma unroll
                for (int j = 0; j < 4; ++j)
                    acc[i][j] = fmaf(a4[i], b4[j], acc[i][j]);
        }
        __syncthreads();
    }
    float4 bv = make_float4(0.f, 0.f, 0.f, 0.f);
    if (bias) bv = *reinterpret_cast<const float4*>(&bias[j0 + tx*4]);
    #pragma unroll
    for (int r = 0; r < 4; ++r) {
        float4 o;
        o.x = acc[r][0] + bv.x; o.y = acc[r][1] + bv.y;
        o.z = acc[r][2] + bv.z; o.w = acc[r][3] + bv.w;
        *reinterpret_cast<float4*>(
            &C[(size_t)(i0 + ty*4 + r) * ldc + j0 + tx*4]) = o;
    }
}

// b'[j] = sum_d bq[d] * Wk[d][j]
__global__ __launch_bounds__(256)
void bias_proj_k(const float* __restrict__ bq, const float* __restrict__ Wk,
                 float* __restrict__ bp)
{
    const int j = blockIdx.x * 256 + threadIdx.x;
    float s = 0.f;
    for (int d = 0; d < 1024; ++d) s = fmaf(bq[d], Wk[d * 1024 + j], s);
    bp[j] = s;
}

// fp32-out softmax (fallback path)
__global__ __launch_bounds__(256)
void softmax_rows_k(float* __restrict__ S, const int* __restrict__ mask)
{
    const int t = threadIdx.x;
    float* srow = S + (size_t)blockIdx.x * 4096;
    float4 v[4];
    float lmax = -INFINITY;
    #pragma unroll
    for (int c = 0; c < 4; ++c) {
        const int idx = c * 1024 + t * 4;
        v[c] = *reinterpret_cast<const float4*>(&srow[idx]);
        const int4 m4 = *reinterpret_cast<const int4*>(&mask[idx]);
        if (m4.x) v[c].x = -INFINITY;
        if (m4.y) v[c].y = -INFINITY;
        if (m4.z) v[c].z = -INFINITY;
        if (m4.w) v[c].w = -INFINITY;
        lmax = fmaxf(lmax, fmaxf(fmaxf(v[c].x, v[c].y), fmaxf(v[c].z, v[c].w)));
    }
    #pragma unroll
    for (int off = 32; off > 0; off >>= 1)
        lmax = fmaxf(lmax, __shfl_xor(lmax, off));
    __shared__ float redm[4], reds[4];
    if ((t & 63) == 0) redm[t >> 6] = lmax;
    __syncthreads();
    const float bmax = fmaxf(fmaxf(redm[0], redm[1]), fmaxf(redm[2], redm[3]));
    float lsum = 0.f;
    #pragma unroll
    for (int c = 0; c < 4; ++c) {
        v[c].x = __expf(v[c].x - bmax);
        v[c].y = __expf(v[c].y - bmax);
        v[c].z = __expf(v[c].z - bmax);
        v[c].w = __expf(v[c].w - bmax);
        lsum += (v[c].x + v[c].y) + (v[c].z + v[c].w);
    }
    #pragma unroll
    for (int off = 32; off > 0; off >>= 1)
        lsum += __shfl_xor(lsum, off);
    if ((t & 63) == 0) reds[t >> 6] = lsum;
    __syncthreads();
    const float Z = (reds[0] + reds[1]) + (reds[2] + reds[3]);
    const float inv = 1.0f / Z;
    #pragma unroll
    for (int c = 0; c < 4; ++c) {
        const int idx = c * 1024 + t * 4;
        float4 o;
        o.x = v[c].x * inv; o.y = v[c].y * inv;
        o.z = v[c].z * inv; o.w = v[c].w * inv;
        *reinterpret_cast<float4*>(&srow[idx]) = o;
    }
}

// ---------------------------------------------------------------------------
// Conversion kernels (MFMA path)
// ---------------------------------------------------------------------------
__global__ __launch_bounds__(256)
void split_k(const float* __restrict__ x, ushort* __restrict__ hi,
             ushort* __restrict__ lo, int n4)
{
    for (int i = blockIdx.x * 256 + threadIdx.x; i < n4; i += gridDim.x * 256) {
        const float4 v = reinterpret_cast<const float4*>(x)[i];
        ushort4 h, l;
        split2(v.x, h.x, l.x); split2(v.y, h.y, l.y);
        split2(v.z, h.z, l.z); split2(v.w, h.w, l.w);
        reinterpret_cast<ushort4*>(hi)[i] = h;
        if (lo) reinterpret_cast<ushort4*>(lo)[i] = l;
    }
}

// out[c][r] = in[r][c] (split to hi/lo bf16; lo optional). grid (C/32, R/32).
__global__ __launch_bounds__(256)
void trans_split_k(const float* __restrict__ in, ushort* __restrict__ oh,
                   ushort* __restrict__ ol, int R, int C)
{
    __shared__ float ts[32][33];
    const int t = threadIdx.x, tx = t & 31, tg = t >> 5;
    const int r0 = blockIdx.y * 32, c0 = blockIdx.x * 32;
    #pragma unroll
    for (int i = 0; i < 4; ++i) {
        const int r = tg * 4 + i;
        ts[r][tx] = in[(size_t)(r0 + r) * C + c0 + tx];
    }
    __syncthreads();
    #pragma unroll
    for (int i = 0; i < 4; ++i) {
        const int c = tg * 4 + i;
        const float v = ts[tx][c];
        ushort h, l; split2(v, h, l);
        const size_t o = (size_t)(c0 + c) * R + r0 + tx;
        oh[o] = h;
        if (ol) ol[o] = l;
    }
}

// masked softmax over 4096-wide rows of fp32 S -> bf16 P
__global__ __launch_bounds__(256)
void softmax_bf16_k(const float* __restrict__ S, const int* __restrict__ mask,
                    ushort* __restrict__ P)
{
    const int t = threadIdx.x;
    const float* srow = S + (size_t)blockIdx.x * 4096;
    ushort* prow = P + (size_t)blockIdx.x * 4096;
    float4 v[4];
    float lmax = -INFINITY;
    #pragma unroll
    for (int c = 0; c < 4; ++c) {
        const int idx = c * 1024 + t * 4;
        v[c] = *reinterpret_cast<const float4*>(&srow[idx]);
        const int4 m4 = *reinterpret_cast<const int4*>(&mask[idx]);
        if (m4.x) v[c].x = -INFINITY;
        if (m4.y) v[c].y = -INFINITY;
        if (m4.z) v[c].z = -INFINITY;
        if (m4.w) v[c].w = -INFINITY;
        lmax = fmaxf(lmax, fmaxf(fmaxf(v[c].x, v[c].y), fmaxf(v[c].z, v[c].w)));
    }
    #pragma unroll
    for (int off = 32; off > 0; off >>= 1)
        lmax = fmaxf(lmax, __shfl_xor(lmax, off));
    __shared__ float redm[4], reds[4];
    if ((t & 63) == 0) redm[t >> 6] = lmax;
    __syncthreads();
    const float bmax = fmaxf(fmaxf(redm[0], redm[1]), fmaxf(redm[2], redm[3]));
    float lsum = 0.f;
    #pragma unroll
    for (int c = 0; c < 4; ++c) {
        v[c].x = __expf(v[c].x - bmax);
        v[c].y = __expf(v[c].y - bmax);
        v[c].z = __expf(v[c].z - bmax);
        v[c].w = __expf(v[c].w - bmax);
        lsum += (v[c].x + v[c].y) + (v[c].z + v[c].w);
    }
    #pragma unroll
    for (int off = 32; off > 0; off >>= 1)
        lsum += __shfl_xor(lsum, off);
    if ((t & 63) == 0) reds[t >> 6] = lsum;
    __syncthreads();
    const float Z = (reds[0] + reds[1]) + (reds[2] + reds[3]);
    const float inv = 1.0f / Z;
    #pragma unroll
    for (int c = 0; c < 4; ++c) {
        const int idx = c * 1024 + t * 4;
        ushort4 o;
        o.x = f2bf_u(v[c].x * inv); o.y = f2bf_u(v[c].y * inv);
        o.z = f2bf_u(v[c].z * inv); o.w = f2bf_u(v[c].w * inv);
        *reinterpret_cast<ushort4*>(&prow[idx]) = o;
    }
}

// ---------------------------------------------------------------------------
// MFMA GEMM: C[M][N] = A[M][K] * B^T (B stored [N][K]), bf16 inputs, fp32 acc.
// SPLIT==3: A,B given as hi/lo pairs; acc = Ah*Bh + Ah*Bl + Al*Bh.
// OUTMODE: 0 = fp32, 1 = bf16, 2 = bf16 hi/lo pair. BK=32, 4 waves (2x2).
// LDS: linear [row][4 x 16B slots], k-slot XOR-swizzled via pre-swizzled
// global source (global_load_lds writes linearly).
// ---------------------------------------------------------------------------
template<int TR>
__device__ inline void stage_one(const ushort* __restrict__ g, int ld, int r0,
                                 int k0, ushort* ldsbase, int w, int l)
{
    constexpr int ISS = TR / 64;   // 1KB issues per wave for this tile
    #pragma unroll
    for (int q = 0; q < ISS; ++q) {
        const int idx = (w * ISS + q) * 64 + l;           // 16B-slot id
        const int row = idx >> 2;
        const int gslot = (idx & 3) ^ ((idx >> 3) & 3);   // pre-swizzled source
        const ushort* src = g + (size_t)(r0 + row) * ld + k0 + gslot * 8;
        ushort* dst = ldsbase + (size_t)(w * ISS + q) * 512;  // wave-uniform
        __builtin_amdgcn_global_load_lds(
            (const __attribute__((address_space(1))) void*)src,
            (__attribute__((address_space(3))) void*)dst, 16, 0, 0);
    }
}

template<int BM, int BN, int SPLIT, int OUTMODE>
__global__ __launch_bounds__(256, 2)
void mfma_gemm_k(const ushort* __restrict__ Ah, const ushort* __restrict__ Al,
                 const ushort* __restrict__ Bh, const ushort* __restrict__ Bl,
                 const float* __restrict__ bias,
                 float* __restrict__ Cf, ushort* __restrict__ Ch,
                 ushort* __restrict__ Cl,
                 int K, int lda, int ldb, int ldc)
{
    constexpr int FM = BM / 32, FN = BN / 32;
    constexpr int NT = (SPLIT == 3) ? 2 : 1;
    constexpr int TILE_U = (BM + BN) * 32;      // ushorts per (A,B) set
    __shared__ __align__(16) ushort lds[2][NT * TILE_U];

    const int t = threadIdx.x;
    const int l = t & 63, w = t >> 6;
    const int lr = l & 15, ls = l >> 4;
    const int i0 = blockIdx.y * BM, j0 = blockIdx.x * BN;
    const int wr = (w >> 1) * (BM / 2), wc = (w & 1) * (BN / 2);
    const int swu = (ls ^ ((lr >> 1) & 3)) * 8; // swizzled k-slot (ushort units)

    f32x4 acc[FM][FN] = {};
    const int nk = K >> 5;

    auto stage = [&](int buf, int kt) {
        const int k0 = kt << 5;
        ushort* base = &lds[buf][0];
        stage_one<BM>(Ah, lda, i0, k0, base, w, l);
        stage_one<BN>(Bh, ldb, j0, k0, base + BM * 32, w, l);
        if constexpr (SPLIT == 3) {
            stage_one<BM>(Al, lda, i0, k0, base + TILE_U, w, l);
            stage_one<BN>(Bl, ldb, j0, k0, base + TILE_U + BM * 32, w, l);
        }
    };

    stage(0, 0);
    for (int kt = 0; kt < nk; ++kt) {
        __syncthreads();                 // drains vmcnt: current buf staged
        const int buf = kt & 1;
        if (kt + 1 < nk) stage(buf ^ 1, kt + 1);
        const ushort* base = &lds[buf][0];

        short8 ah[FM], bh[FN];
        #pragma unroll
        for (int fi = 0; fi < FM; ++fi)
            ah[fi] = *reinterpret_cast<const short8*>(
                base + (wr + fi * 16 + lr) * 32 + swu);
        #pragma unroll
        for (int fj = 0; fj < FN; ++fj)
            bh[fj] = *reinterpret_cast<const short8*>(
                base + BM * 32 + (wc + fj * 16 + lr) * 32 + swu);

        if constexpr (SPLIT == 3) {
            short8 al[FM], bl[FN];
            #pragma unroll
            for (int fi = 0; fi < FM; ++fi)
                al[fi] = *reinterpret_cast<const short8*>(
                    base + TILE_U + (wr + fi * 16 + lr) * 32 + swu);
            #pragma unroll
            for (int fj = 0; fj < FN; ++fj)
                bl[fj] = *reinterpret_cast<const short8*>(
                    base + TILE_U + BM * 32 + (wc + fj * 16 + lr) * 32 + swu);
            #pragma unroll
            for (int fi = 0; fi < FM; ++fi)
                #pragma unroll
                for (int fj = 0; fj < FN; ++fj) {
                    acc[fi][fj] = __builtin_amdgcn_mfma_f32_16x16x32_bf16(
                        ah[fi], bh[fj], acc[fi][fj], 0, 0, 0);
                    acc[fi][fj] = __builtin_amdgcn_mfma_f32_16x16x32_bf16(
                        ah[fi], bl[fj], acc[fi][fj], 0, 0, 0);
                    acc[fi][fj] = __builtin_amdgcn_mfma_f32_16x16x32_bf16(
                        al[fi], bh[fj], acc[fi][fj], 0, 0, 0);
                }
        } else {
            #pragma unroll
            for (int fi = 0; fi < FM; ++fi)
                #pragma unroll
                for (int fj = 0; fj < FN; ++fj)
                    acc[fi][fj] = __builtin_amdgcn_mfma_f32_16x16x32_bf16(
                        ah[fi], bh[fj], acc[fi][fj], 0, 0, 0);
        }
    }

    // epilogue: C/D layout col=lane&15, row=(lane>>4)*4+reg
    #pragma unroll
    for (int fj = 0; fj < FN; ++fj) {
        const int gc = j0 + wc + fj * 16 + lr;
        const float bv = bias ? bias[gc] : 0.0f;
        #pragma unroll
        for (int fi = 0; fi < FM; ++fi) {
            const int gr = i0 + wr + fi * 16 + ls * 4;
            #pragma unroll
            for (int r = 0; r < 4; ++r) {
                const float v = acc[fi][fj][r] + bv;
                const size_t o = (size_t)(gr + r) * ldc + gc;
                if constexpr (OUTMODE == 0) {
                    Cf[o] = v;
                } else if constexpr (OUTMODE == 1) {
                    Ch[o] = f2bf_u(v);
                } else {
                    const ushort h = f2bf_u(v);
                    Ch[o] = h;
                    Cl[o] = f2bf_u(v - bfu2f(h));
                }
            }
        }
    }
}

// ---------------------------------------------------------------------------
extern "C" void kernel_launch(void* const* d_in, const int* in_sizes, int n_in,
                              void* d_out, int out_size, void* d_ws, size_t ws_size,
                              hipStream_t stream)
{
    (void)in_sizes; (void)n_in; (void)out_size;
    const int NB = 8, LQ = 1024, LI = 4096, D = 1024;

    const float* query = (const float*)d_in[0];
    const float* input = (const float*)d_in[1];
    const int* mask = (const int*)d_in[2];   // bool -> int32 on device
    const float* Wq = (const float*)d_in[3];
    const float* bq = (const float*)d_in[4];
    const float* Wk = (const float*)d_in[5];
    /* d_in[6] = bk: cancels in softmax */
    const float* Wo = (const float*)d_in[7];
    const float* bo = (const float*)d_in[8];
    float* out = (float*)d_out;

    dim3 blk(256);

    // ---- MFMA-path workspace layout ----
    char* p = (char*)d_ws;
    auto alloc = [&](size_t bytes) {
        char* r = p; p += (bytes + 255) & ~(size_t)255; return r;
    };
    float*  Wp   = (float*) alloc((size_t)D * D * 4);       // W' fp32
    float*  bp   = (float*) alloc((size_t)D * 4);           // b'
    float*  S    = (float*) alloc((size_t)LQ * LI * 4);     // scores (per batch)
    ushort* qh   = (ushort*)alloc((size_t)NB * LQ * D * 2); // query hi
    ushort* ql   = (ushort*)alloc((size_t)NB * LQ * D * 2);
    ushort* WTh  = (ushort*)alloc((size_t)D * D * 2);       // W'^T hi
    ushort* WTl  = (ushort*)alloc((size_t)D * D * 2);
    ushort* Qh   = (ushort*)alloc((size_t)NB * LQ * D * 2); // Q'' hi
    ushort* Ql   = (ushort*)alloc((size_t)NB * LQ * D * 2);
    ushort* inh  = (ushort*)alloc((size_t)LI * D * 2);      // K hi (per batch)
    ushort* inl  = (ushort*)alloc((size_t)LI * D * 2);
    ushort* VT   = (ushort*)alloc((size_t)D * LI * 2);      // V^T bf16 (per batch)
    ushort* Pb   = (ushort*)alloc((size_t)LQ * LI * 2);     // P bf16 (per batch)
    ushort* Ob   = (ushort*)alloc((size_t)NB * LQ * D * 2); // O bf16
    ushort* Wob  = (ushort*)alloc((size_t)D * D * 2);       // Wo bf16
    const size_t needed = (size_t)(p - (char*)d_ws);

    if (needed <= ws_size) {
        // ================= MFMA path =================
        // W' = Wq^T @ Wk (fp32, precision-critical, tiny)
        gemm_k<true, false><<<dim3(16, 16), blk, 0, stream>>>(
            Wq, Wk, nullptr, Wp, D, D, D, D, D, D);
        // W'^T -> hi/lo bf16 ([N][K] layout for MFMA B-operand)
        trans_split_k<<<dim3(32, 32), blk, 0, stream>>>(Wp, WTh, WTl, D, D);
        // b' = bq @ Wk
        bias_proj_k<<<dim3(4), blk, 0, stream>>>(bq, Wk, bp);
        // query -> hi/lo
        split_k<<<dim3(2048), blk, 0, stream>>>(query, qh, ql, NB * LQ * D / 4);
        // Wo -> bf16 (already [N][K] for out-proj B-operand)
        split_k<<<dim3(1024), blk, 0, stream>>>(Wo, Wob, nullptr, D * D / 4);
        // Q'' = query @ W' + b'  (split-3, writes hi/lo pair)
        mfma_gemm_k<128, 128, 3, 2><<<dim3(D / 128, NB * LQ / 128), blk, 0, stream>>>(
            qh, ql, WTh, WTl, bp, nullptr, Qh, Ql, D, D, D, D);

        for (int b = 0; b < NB; ++b) {
            const float* in_b = input + (size_t)b * LI * D;
            // K hi/lo
            split_k<<<dim3(2048), blk, 0, stream>>>(in_b, inh, inl, LI * D / 4);
            // V^T bf16
            trans_split_k<<<dim3(32, 128), blk, 0, stream>>>(in_b, VT, nullptr, LI, D);
            // S = Q''_b @ input_b^T (split-3, fp32 out)
            mfma_gemm_k<128, 64, 3, 0><<<dim3(LI / 64, LQ / 128), blk, 0, stream>>>(
                Qh + (size_t)b * LQ * D, Ql + (size_t)b * LQ * D, inh, inl,
                nullptr, S, nullptr, nullptr, D, D, D, LI);
            // masked softmax -> P bf16
            softmax_bf16_k<<<dim3(LQ), blk, 0, stream>>>(S, mask + (size_t)b * LI, Pb);
            // O_b = P @ V  (plain bf16, bf16 out)
            mfma_gemm_k<64, 64, 1, 1><<<dim3(D / 64, LQ / 64), blk, 0, stream>>>(
                Pb, nullptr, VT, nullptr, nullptr, nullptr,
                Ob + (size_t)b * LQ * D, nullptr, LI, LI, LI, D);
        }
        // out = O @ Wo^T + bo (fp32 out)
        mfma_gemm_k<128, 128, 1, 0><<<dim3(D / 128, NB * LQ / 128), blk, 0, stream>>>(
            Ob, nullptr, Wob, nullptr, bo, out, nullptr, nullptr, D, D, D, D);
    } else {
        // ================= fp32 fallback (R3, proven) =================
        float* Wp2  = (float*)d_ws;
        float* bp2  = Wp2 + (size_t)D * D;
        float* Qpp  = bp2 + D;
        float* S2   = Qpp + (size_t)NB * LQ * D;
        float* O2   = S2 + (size_t)LQ * LI;
        gemm_k<true, false><<<dim3(16, 16), blk, 0, stream>>>(
            Wq, Wk, nullptr, Wp2, D, D, D, D, D, D);
        bias_proj_k<<<dim3(4), blk, 0, stream>>>(bq, Wk, bp2);
        gemm_k<false, false><<<dim3(16, 128), blk, 0, stream>>>(
            query, Wp2, bp2, Qpp, NB * LQ, D, D, D, D, D);
        for (int n = 0; n < NB; ++n) {
            const float* inp_n = input + (size_t)n * LI * D;
            gemm_k<false, true><<<dim3(64, 16), blk, 0, stream>>>(
                Qpp + (size_t)n * LQ * D, inp_n, nullptr, S2, LQ, LI, D, D, D, LI);
            softmax_rows_k<<<dim3(LQ), blk, 0, stream>>>(S2, mask + (size_t)n * LI);
            gemm_k<false, false><<<dim3(16, 16), blk, 0, stream>>>(
                S2, inp_n, nullptr, O2 + (size_t)n * LQ * D, LQ, D, LI, LI, D, D);
        }
        gemm_k<false, true><<<dim3(16, 128), blk, 0, stream>>>(
            O2, Wo, bo, out, NB * LQ, D, D, D, D, D);
    }
}

// Round 6
// 640.569 us; speedup vs baseline: 5.2849x; 1.4650x over previous
//
#include <hip/hip_runtime.h>
#include <hip/hip_bf16.h>
#include <math.h>

// CrossAttention (N=8, Lq=1024, Lk=4096, D=1024), fp32 in/out.
// scores = Q''*input^T (+row const); Q'' = query*(Wq^T*Wk) + bq*Wk; bk cancels.
// V = unprojected input. out = (P*V)*Wo^T + bo.
// Precision: split-bf16 (hi+lo, 3-MFMA) on the score path; plain bf16 PV/out-proj.
// ws_size = 512 MiB (measured via harness poison fill) -> fully batched buffers.

using short8 = __attribute__((ext_vector_type(8))) short;
using f32x4  = __attribute__((ext_vector_type(4))) float;

__device__ inline ushort f2bf_u(float f) {
    __hip_bfloat16 b = __float2bfloat16(f);
    return __builtin_bit_cast(ushort, b);
}
__device__ inline float bfu2f(ushort u) {
    __hip_bfloat16 b = __builtin_bit_cast(__hip_bfloat16, u);
    return __bfloat162float(b);
}
__device__ inline void split2(float x, ushort& h, ushort& l) {
    const ushort hu = f2bf_u(x);
    h = hu;
    l = f2bf_u(x - bfu2f(hu));
}

// b'[j] = sum_d bq[d] * Wk[d][j]
__global__ __launch_bounds__(256)
void bias_proj_k(const float* __restrict__ bq, const float* __restrict__ Wk,
                 float* __restrict__ bp)
{
    const int j = blockIdx.x * 256 + threadIdx.x;
    float s = 0.f;
    for (int d = 0; d < 1024; ++d) s = fmaf(bq[d], Wk[d * 1024 + j], s);
    bp[j] = s;
}

// fp32 -> bf16 hi/lo split (lo optional), grid-stride over float4s
__global__ __launch_bounds__(256)
void split_k(const float* __restrict__ x, ushort* __restrict__ hi,
             ushort* __restrict__ lo, int n4)
{
    for (int i = blockIdx.x * 256 + threadIdx.x; i < n4; i += gridDim.x * 256) {
        const float4 v = reinterpret_cast<const float4*>(x)[i];
        ushort4 h, l;
        split2(v.x, h.x, l.x); split2(v.y, h.y, l.y);
        split2(v.z, h.z, l.z); split2(v.w, h.w, l.w);
        reinterpret_cast<ushort4*>(hi)[i] = h;
        if (lo) reinterpret_cast<ushort4*>(lo)[i] = l;
    }
}

// out[c][r] = in[r][c] with hi/lo split (lo optional). grid (C/32, R/32, NB).
__global__ __launch_bounds__(256)
void trans_split_k(const float* __restrict__ in, ushort* __restrict__ oh,
                   ushort* __restrict__ ol, int R, int C,
                   long long ibs, long long obs)
{
    __shared__ float ts[32][33];
    const int t = threadIdx.x, tx = t & 31, tg = t >> 5;
    const int r0 = blockIdx.y * 32, c0 = blockIdx.x * 32;
    const long long z = blockIdx.z;
    in += z * ibs; oh += z * obs;
    if (ol) ol += z * obs;
    #pragma unroll
    for (int i = 0; i < 4; ++i) {
        const int r = tg * 4 + i;
        ts[r][tx] = in[(size_t)(r0 + r) * C + c0 + tx];
    }
    __syncthreads();
    #pragma unroll
    for (int i = 0; i < 4; ++i) {
        const int c = tg * 4 + i;
        const float v = ts[tx][c];
        ushort h, l; split2(v, h, l);
        const size_t o = (size_t)(c0 + c) * R + r0 + tx;
        oh[o] = h;
        if (ol) ol[o] = l;
    }
}

// masked softmax over 4096-wide rows of fp32 S -> bf16 P. grid (LQ, NB).
__global__ __launch_bounds__(256)
void softmax_bf16_k(const float* __restrict__ S, const int* __restrict__ mask,
                    ushort* __restrict__ P)
{
    const int t = threadIdx.x;
    const size_t row = (size_t)blockIdx.y * gridDim.x + blockIdx.x;
    const float* srow = S + row * 4096;
    ushort* prow = P + row * 4096;
    mask += (size_t)blockIdx.y * 4096;
    float4 v[4];
    float lmax = -INFINITY;
    #pragma unroll
    for (int c = 0; c < 4; ++c) {
        const int idx = c * 1024 + t * 4;
        v[c] = *reinterpret_cast<const float4*>(&srow[idx]);
        const int4 m4 = *reinterpret_cast<const int4*>(&mask[idx]);
        if (m4.x) v[c].x = -INFINITY;
        if (m4.y) v[c].y = -INFINITY;
        if (m4.z) v[c].z = -INFINITY;
        if (m4.w) v[c].w = -INFINITY;
        lmax = fmaxf(lmax, fmaxf(fmaxf(v[c].x, v[c].y), fmaxf(v[c].z, v[c].w)));
    }
    #pragma unroll
    for (int off = 32; off > 0; off >>= 1)
        lmax = fmaxf(lmax, __shfl_xor(lmax, off));
    __shared__ float redm[4], reds[4];
    if ((t & 63) == 0) redm[t >> 6] = lmax;
    __syncthreads();
    const float bmax = fmaxf(fmaxf(redm[0], redm[1]), fmaxf(redm[2], redm[3]));
    float lsum = 0.f;
    #pragma unroll
    for (int c = 0; c < 4; ++c) {
        v[c].x = __expf(v[c].x - bmax);
        v[c].y = __expf(v[c].y - bmax);
        v[c].z = __expf(v[c].z - bmax);
        v[c].w = __expf(v[c].w - bmax);
        lsum += (v[c].x + v[c].y) + (v[c].z + v[c].w);
    }
    #pragma unroll
    for (int off = 32; off > 0; off >>= 1)
        lsum += __shfl_xor(lsum, off);
    if ((t & 63) == 0) reds[t >> 6] = lsum;
    __syncthreads();
    const float Z = (reds[0] + reds[1]) + (reds[2] + reds[3]);
    const float inv = 1.0f / Z;
    #pragma unroll
    for (int c = 0; c < 4; ++c) {
        const int idx = c * 1024 + t * 4;
        ushort4 o;
        o.x = f2bf_u(v[c].x * inv); o.y = f2bf_u(v[c].y * inv);
        o.z = f2bf_u(v[c].z * inv); o.w = f2bf_u(v[c].w * inv);
        *reinterpret_cast<ushort4*>(&prow[idx]) = o;
    }
}

// ---------------------------------------------------------------------------
// MFMA GEMM: C[M][N] = A[M][K] * B^T (B stored [N][K]), bf16 in, fp32 acc.
// SPLIT==3: hi/lo pairs, acc = Ah*Bh + Ah*Bl + Al*Bh. OUTMODE: 0 fp32,
// 1 bf16, 2 bf16 hi/lo pair. BK=32, 4 waves (2x2). blockIdx.z = batch with
// element strides bsA/bsB/bsC. LDS k-slot XOR-swizzle via pre-swizzled
// global source (global_load_lds writes linearly; swizzles cancel on read).
// ---------------------------------------------------------------------------
template<int TR>
__device__ inline void stage_one(const ushort* __restrict__ g, int ld, int r0,
                                 int k0, ushort* ldsbase, int w, int l)
{
    constexpr int ISS = TR / 64;
    #pragma unroll
    for (int q = 0; q < ISS; ++q) {
        const int idx = (w * ISS + q) * 64 + l;           // 16B-slot id
        const int row = idx >> 2;
        const int gslot = (idx & 3) ^ ((idx >> 3) & 3);   // pre-swizzled source
        const ushort* src = g + (size_t)(r0 + row) * ld + k0 + gslot * 8;
        ushort* dst = ldsbase + (size_t)(w * ISS + q) * 512;  // wave-uniform
        __builtin_amdgcn_global_load_lds(
            (const __attribute__((address_space(1))) void*)src,
            (__attribute__((address_space(3))) void*)dst, 16, 0, 0);
    }
}

template<int BM, int BN, int SPLIT, int OUTMODE>
__global__ __launch_bounds__(256, 2)
void mfma_gemm_k(const ushort* __restrict__ Ah, const ushort* __restrict__ Al,
                 const ushort* __restrict__ Bh, const ushort* __restrict__ Bl,
                 const float* __restrict__ bias,
                 float* __restrict__ Cf, ushort* __restrict__ Ch,
                 ushort* __restrict__ Cl,
                 int K, int lda, int ldb, int ldc,
                 long long bsA, long long bsB, long long bsC)
{
    constexpr int FM = BM / 32, FN = BN / 32;
    constexpr int NT = (SPLIT == 3) ? 2 : 1;
    constexpr int TILE_U = (BM + BN) * 32;      // ushorts per (A,B) set
    __shared__ __align__(16) ushort lds[2][NT * TILE_U];

    const long long zb = blockIdx.z;
    Ah += zb * bsA; Bh += zb * bsB;
    if constexpr (SPLIT == 3) { Al += zb * bsA; Bl += zb * bsB; }

    const int t = threadIdx.x;
    const int l = t & 63, w = t >> 6;
    const int lr = l & 15, ls = l >> 4;
    const int i0 = blockIdx.y * BM, j0 = blockIdx.x * BN;
    const int wr = (w >> 1) * (BM / 2), wc = (w & 1) * (BN / 2);
    const int swu = (ls ^ ((lr >> 1) & 3)) * 8; // swizzled k-slot (ushorts)

    f32x4 acc[FM][FN] = {};
    const int nk = K >> 5;

    auto stage = [&](int buf, int kt) {
        const int k0 = kt << 5;
        ushort* base = &lds[buf][0];
        stage_one<BM>(Ah, lda, i0, k0, base, w, l);
        stage_one<BN>(Bh, ldb, j0, k0, base + BM * 32, w, l);
        if constexpr (SPLIT == 3) {
            stage_one<BM>(Al, lda, i0, k0, base + TILE_U, w, l);
            stage_one<BN>(Bl, ldb, j0, k0, base + TILE_U + BM * 32, w, l);
        }
    };

    stage(0, 0);
    for (int kt = 0; kt < nk; ++kt) {
        __syncthreads();                 // drains vmcnt: current buf staged
        const int buf = kt & 1;
        if (kt + 1 < nk) stage(buf ^ 1, kt + 1);
        const ushort* base = &lds[buf][0];

        short8 ah[FM], bh[FN];
        #pragma unroll
        for (int fi = 0; fi < FM; ++fi)
            ah[fi] = *reinterpret_cast<const short8*>(
                base + (wr + fi * 16 + lr) * 32 + swu);
        #pragma unroll
        for (int fj = 0; fj < FN; ++fj)
            bh[fj] = *reinterpret_cast<const short8*>(
                base + BM * 32 + (wc + fj * 16 + lr) * 32 + swu);

        if constexpr (SPLIT == 3) {
            short8 al[FM], bl[FN];
            #pragma unroll
            for (int fi = 0; fi < FM; ++fi)
                al[fi] = *reinterpret_cast<const short8*>(
                    base + TILE_U + (wr + fi * 16 + lr) * 32 + swu);
            #pragma unroll
            for (int fj = 0; fj < FN; ++fj)
                bl[fj] = *reinterpret_cast<const short8*>(
                    base + TILE_U + BM * 32 + (wc + fj * 16 + lr) * 32 + swu);
            #pragma unroll
            for (int fi = 0; fi < FM; ++fi)
                #pragma unroll
                for (int fj = 0; fj < FN; ++fj) {
                    acc[fi][fj] = __builtin_amdgcn_mfma_f32_16x16x32_bf16(
                        ah[fi], bh[fj], acc[fi][fj], 0, 0, 0);
                    acc[fi][fj] = __builtin_amdgcn_mfma_f32_16x16x32_bf16(
                        ah[fi], bl[fj], acc[fi][fj], 0, 0, 0);
                    acc[fi][fj] = __builtin_amdgcn_mfma_f32_16x16x32_bf16(
                        al[fi], bh[fj], acc[fi][fj], 0, 0, 0);
                }
        } else {
            #pragma unroll
            for (int fi = 0; fi < FM; ++fi)
                #pragma unroll
                for (int fj = 0; fj < FN; ++fj)
                    acc[fi][fj] = __builtin_amdgcn_mfma_f32_16x16x32_bf16(
                        ah[fi], bh[fj], acc[fi][fj], 0, 0, 0);
        }
    }

    // epilogue: C/D layout col=lane&15, row=(lane>>4)*4+reg
    #pragma unroll
    for (int fj = 0; fj < FN; ++fj) {
        const int gc = j0 + wc + fj * 16 + lr;
        const float bv = bias ? bias[gc] : 0.0f;
        #pragma unroll
        for (int fi = 0; fi < FM; ++fi) {
            const int gr = i0 + wr + fi * 16 + ls * 4;
            #pragma unroll
            for (int r = 0; r < 4; ++r) {
                const float v = acc[fi][fj][r] + bv;
                const size_t o = zb * bsC + (size_t)(gr + r) * ldc + gc;
                if constexpr (OUTMODE == 0) {
                    Cf[o] = v;
                } else if constexpr (OUTMODE == 1) {
                    Ch[o] = f2bf_u(v);
                } else {
                    const ushort h = f2bf_u(v);
                    Ch[o] = h;
                    Cl[o] = f2bf_u(v - bfu2f(h));
                }
            }
        }
    }
}

// ---------------------------------------------------------------------------
extern "C" void kernel_launch(void* const* d_in, const int* in_sizes, int n_in,
                              void* d_out, int out_size, void* d_ws, size_t ws_size,
                              hipStream_t stream)
{
    (void)in_sizes; (void)n_in; (void)out_size;
    const int NB = 8, LQ = 1024, LI = 4096, D = 1024;
    const long long sQD = (long long)LQ * D;   // 1M
    const long long sID = (long long)LI * D;   // 4M
    const long long sQI = (long long)LQ * LI;  // 4M

    const float* query = (const float*)d_in[0];
    const float* input = (const float*)d_in[1];
    const int* mask = (const int*)d_in[2];   // bool -> int32 on device
    const float* Wq = (const float*)d_in[3];
    const float* bq = (const float*)d_in[4];
    const float* Wk = (const float*)d_in[5];
    /* d_in[6] = bk: cancels in softmax */
    const float* Wo = (const float*)d_in[7];
    const float* bo = (const float*)d_in[8];
    float* out = (float*)d_out;

    dim3 blk(256);

    char* p = (char*)d_ws;
    auto alloc = [&](size_t bytes) {
        char* r = p; p += (bytes + 255) & ~(size_t)255; return r;
    };
    // head buffers (both paths)
    ushort* qh   = (ushort*)alloc((size_t)NB * sQD * 2);
    ushort* ql   = (ushort*)alloc((size_t)NB * sQD * 2);
    ushort* WqTh = (ushort*)alloc((size_t)D * D * 2);
    ushort* WqTl = (ushort*)alloc((size_t)D * D * 2);
    ushort* WkTh = (ushort*)alloc((size_t)D * D * 2);
    ushort* WkTl = (ushort*)alloc((size_t)D * D * 2);
    ushort* WTh  = (ushort*)alloc((size_t)D * D * 2);
    ushort* WTl  = (ushort*)alloc((size_t)D * D * 2);
    float*  bp   = (float*) alloc((size_t)D * 4);
    ushort* Qh   = (ushort*)alloc((size_t)NB * sQD * 2);
    ushort* Ql   = (ushort*)alloc((size_t)NB * sQD * 2);
    ushort* Ob   = (ushort*)alloc((size_t)NB * sQD * 2);
    ushort* Wob  = (ushort*)alloc((size_t)D * D * 2);
    char* tail = p;

    // full-batch tail
    ushort* inh = (ushort*)alloc((size_t)NB * sID * 2);
    ushort* inl = (ushort*)alloc((size_t)NB * sID * 2);
    ushort* VT  = (ushort*)alloc((size_t)NB * sID * 2);
    float*  S   = (float*) alloc((size_t)NB * sQI * 4);
    ushort* Pb  = (ushort*)alloc((size_t)NB * sQI * 2);
    const bool full = (size_t)(p - (char*)d_ws) <= ws_size;
    if (!full) {
        // per-batch tail (R5-proven footprint)
        p = tail;
        inh = (ushort*)alloc((size_t)sID * 2);
        inl = (ushort*)alloc((size_t)sID * 2);
        VT  = (ushort*)alloc((size_t)sID * 2);
        S   = (float*) alloc((size_t)sQI * 4);
        Pb  = (ushort*)alloc((size_t)sQI * 2);
    }

    // ---- head: W'^T = Wk^T @ (Wq^T)^T via split-3 MFMA ----
    trans_split_k<<<dim3(32, 32, 1), blk, 0, stream>>>(Wq, WqTh, WqTl, D, D, 0, 0);
    trans_split_k<<<dim3(32, 32, 1), blk, 0, stream>>>(Wk, WkTh, WkTl, D, D, 0, 0);
    bias_proj_k<<<dim3(4), blk, 0, stream>>>(bq, Wk, bp);
    mfma_gemm_k<64, 64, 3, 2><<<dim3(16, 16, 1), blk, 0, stream>>>(
        WkTh, WkTl, WqTh, WqTl, nullptr, nullptr, WTh, WTl, D, D, D, D, 0, 0, 0);
    split_k<<<dim3(2048), blk, 0, stream>>>(query, qh, ql, NB * (int)sQD / 4);
    split_k<<<dim3(1024), blk, 0, stream>>>(Wo, Wob, nullptr, D * D / 4);
    // Q'' = query @ W' + b'  (split-3, hi/lo out)
    mfma_gemm_k<128, 128, 3, 2><<<dim3(D / 128, NB * LQ / 128, 1), blk, 0, stream>>>(
        qh, ql, WTh, WTl, bp, nullptr, Qh, Ql, D, D, D, D, 0, 0, 0);

    if (full) {
        split_k<<<dim3(4096), blk, 0, stream>>>(input, inh, inl, NB * (int)sID / 4);
        trans_split_k<<<dim3(D / 32, LI / 32, NB), blk, 0, stream>>>(
            input, VT, nullptr, LI, D, sID, sID);
        // S = Q'' @ input^T (split-3, fp32 out), batched over z
        mfma_gemm_k<128, 128, 3, 0><<<dim3(LI / 128, LQ / 128, NB), blk, 0, stream>>>(
            Qh, Ql, inh, inl, nullptr, S, nullptr, nullptr,
            D, D, D, LI, sQD, sID, sQI);
        softmax_bf16_k<<<dim3(LQ, NB), blk, 0, stream>>>(S, mask, Pb);
        // O = P @ V (plain bf16), batched over z
        mfma_gemm_k<128, 128, 1, 1><<<dim3(D / 128, LQ / 128, NB), blk, 0, stream>>>(
            Pb, nullptr, VT, nullptr, nullptr, nullptr, Ob, nullptr,
            LI, LI, LI, D, sQI, sID, sQD);
    } else {
        for (int b = 0; b < NB; ++b) {
            const float* in_b = input + (size_t)b * sID;
            split_k<<<dim3(2048), blk, 0, stream>>>(in_b, inh, inl, (int)sID / 4);
            trans_split_k<<<dim3(D / 32, LI / 32, 1), blk, 0, stream>>>(
                in_b, VT, nullptr, LI, D, 0, 0);
            mfma_gemm_k<128, 128, 3, 0><<<dim3(LI / 128, LQ / 128, 1), blk, 0, stream>>>(
                Qh + (size_t)b * sQD, Ql + (size_t)b * sQD, inh, inl,
                nullptr, S, nullptr, nullptr, D, D, D, LI, 0, 0, 0);
            softmax_bf16_k<<<dim3(LQ, 1), blk, 0, stream>>>(S, mask + (size_t)b * LI, Pb);
            mfma_gemm_k<128, 128, 1, 1><<<dim3(D / 128, LQ / 128, 1), blk, 0, stream>>>(
                Pb, nullptr, VT, nullptr, nullptr, nullptr,
                Ob + (size_t)b * sQD, nullptr, LI, LI, LI, D, 0, 0, 0);
        }
    }
    // out = O @ Wo^T + bo (fp32 out)
    mfma_gemm_k<128, 128, 1, 0><<<dim3(D / 128, NB * LQ / 128, 1), blk, 0, stream>>>(
        Ob, nullptr, Wob, nullptr, bo, out, nullptr, nullptr, D, D, D, D, 0, 0, 0);
}

// Round 7
// 546.695 us; speedup vs baseline: 6.1924x; 1.1717x over previous
//
#include <hip/hip_runtime.h>
#include <math.h>

// CrossAttention (N=8, Lq=1024, Lk=4096, D=1024), fp32 in/out.
// scores = Q''*input^T (+row const); Q'' = query*(Wq^T*Wk) + bq*Wk; bk cancels.
// V = unprojected input. out = (P*V)*Wo^T + bo.
// Precision: f16 pipeline. Score path: A-single x B-(hi/lo) = 2 MFMAs.
// S kept fp32. P/V/O/Wo plain f16 (better than bf16 by 8x mantissa).

using short8 = __attribute__((ext_vector_type(8))) short;
using f32x4  = __attribute__((ext_vector_type(4))) float;

__device__ inline ushort f2h_u(float f) {
    _Float16 h = (_Float16)f;
    return __builtin_bit_cast(ushort, h);
}
__device__ inline float h2f(ushort u) {
    return (float)__builtin_bit_cast(_Float16, u);
}
__device__ inline void split2h(float x, ushort& h, ushort& l) {
    const ushort hu = f2h_u(x);
    h = hu;
    l = f2h_u(x - h2f(hu));
}

// b'[j] = sum_d bq[d] * Wk[d][j]
__global__ __launch_bounds__(256)
void bias_proj_k(const float* __restrict__ bq, const float* __restrict__ Wk,
                 float* __restrict__ bp)
{
    const int j = blockIdx.x * 256 + threadIdx.x;
    float s = 0.f;
    for (int d = 0; d < 1024; ++d) s = fmaf(bq[d], Wk[d * 1024 + j], s);
    bp[j] = s;
}

// fp32 -> f16 hi (+optional lo), grid-stride over float4s
__global__ __launch_bounds__(256)
void split_k(const float* __restrict__ x, ushort* __restrict__ hi,
             ushort* __restrict__ lo, int n4)
{
    for (int i = blockIdx.x * 256 + threadIdx.x; i < n4; i += gridDim.x * 256) {
        const float4 v = reinterpret_cast<const float4*>(x)[i];
        ushort4 h, l;
        split2h(v.x, h.x, l.x); split2h(v.y, h.y, l.y);
        split2h(v.z, h.z, l.z); split2h(v.w, h.w, l.w);
        reinterpret_cast<ushort4*>(hi)[i] = h;
        if (lo) reinterpret_cast<ushort4*>(lo)[i] = l;
    }
}

// out[c][r] = in[r][c] with f16 hi/lo split. grid (C/32, R/32).
__global__ __launch_bounds__(256)
void trans_split_k(const float* __restrict__ in, ushort* __restrict__ oh,
                   ushort* __restrict__ ol, int R, int C)
{
    __shared__ float ts[32][33];
    const int t = threadIdx.x, tx = t & 31, tg = t >> 5;
    const int r0 = blockIdx.y * 32, c0 = blockIdx.x * 32;
    #pragma unroll
    for (int i = 0; i < 4; ++i) {
        const int r = tg * 4 + i;
        ts[r][tx] = in[(size_t)(r0 + r) * C + c0 + tx];
    }
    __syncthreads();
    #pragma unroll
    for (int i = 0; i < 4; ++i) {
        const int c = tg * 4 + i;
        ushort h, l; split2h(ts[tx][c], h, l);
        const size_t o = (size_t)(c0 + c) * R + r0 + tx;
        oh[o] = h;
        if (ol) ol[o] = l;
    }
}

// Fused: read input [LI][D] fp32 once -> inh/inl f16 [LI][D] + VT f16 [D][LI].
// grid (D/32, LI/32, NB), block 256.
__global__ __launch_bounds__(256)
void prep_input_k(const float* __restrict__ in, ushort* __restrict__ ih,
                  ushort* __restrict__ il, ushort* __restrict__ vt,
                  int LI, int D, long long bs)
{
    __shared__ float ts[32][33];
    const int t = threadIdx.x;
    const int tx8 = t & 7, ty = t >> 3;      // load: 8 threads x float4 per row
    const int r0 = blockIdx.y * 32, c0 = blockIdx.x * 32;
    const long long z = blockIdx.z;
    in += z * bs; ih += z * bs; il += z * bs; vt += z * bs;

    const float4 v = *reinterpret_cast<const float4*>(
        &in[(size_t)(r0 + ty) * D + c0 + tx8 * 4]);
    ushort4 h, l;
    split2h(v.x, h.x, l.x); split2h(v.y, h.y, l.y);
    split2h(v.z, h.z, l.z); split2h(v.w, h.w, l.w);
    *reinterpret_cast<ushort4*>(&ih[(size_t)(r0 + ty) * D + c0 + tx8 * 4]) = h;
    *reinterpret_cast<ushort4*>(&il[(size_t)(r0 + ty) * D + c0 + tx8 * 4]) = l;
    ts[ty][tx8 * 4 + 0] = v.x; ts[ty][tx8 * 4 + 1] = v.y;
    ts[ty][tx8 * 4 + 2] = v.z; ts[ty][tx8 * 4 + 3] = v.w;
    __syncthreads();
    const int tx = t & 31, tg = t >> 5;
    #pragma unroll
    for (int i = 0; i < 4; ++i) {
        const int c = tg * 4 + i;
        vt[(size_t)(c0 + c) * LI + r0 + tx] = f2h_u(ts[tx][c]);
    }
}

// masked softmax over 4096-wide fp32 rows -> f16 P. grid (LQ, NB).
__global__ __launch_bounds__(256)
void softmax_f16_k(const float* __restrict__ S, const int* __restrict__ mask,
                   ushort* __restrict__ P)
{
    const int t = threadIdx.x;
    const size_t row = (size_t)blockIdx.y * gridDim.x + blockIdx.x;
    const float* srow = S + row * 4096;
    ushort* prow = P + row * 4096;
    mask += (size_t)blockIdx.y * 4096;
    float4 v[4];
    float lmax = -INFINITY;
    #pragma unroll
    for (int c = 0; c < 4; ++c) {
        const int idx = c * 1024 + t * 4;
        v[c] = *reinterpret_cast<const float4*>(&srow[idx]);
        const int4 m4 = *reinterpret_cast<const int4*>(&mask[idx]);
        if (m4.x) v[c].x = -INFINITY;
        if (m4.y) v[c].y = -INFINITY;
        if (m4.z) v[c].z = -INFINITY;
        if (m4.w) v[c].w = -INFINITY;
        lmax = fmaxf(lmax, fmaxf(fmaxf(v[c].x, v[c].y), fmaxf(v[c].z, v[c].w)));
    }
    #pragma unroll
    for (int off = 32; off > 0; off >>= 1)
        lmax = fmaxf(lmax, __shfl_xor(lmax, off));
    __shared__ float redm[4], reds[4];
    if ((t & 63) == 0) redm[t >> 6] = lmax;
    __syncthreads();
    const float bmax = fmaxf(fmaxf(redm[0], redm[1]), fmaxf(redm[2], redm[3]));
    float lsum = 0.f;
    #pragma unroll
    for (int c = 0; c < 4; ++c) {
        v[c].x = __expf(v[c].x - bmax);
        v[c].y = __expf(v[c].y - bmax);
        v[c].z = __expf(v[c].z - bmax);
        v[c].w = __expf(v[c].w - bmax);
        lsum += (v[c].x + v[c].y) + (v[c].z + v[c].w);
    }
    #pragma unroll
    for (int off = 32; off > 0; off >>= 1)
        lsum += __shfl_xor(lsum, off);
    if ((t & 63) == 0) reds[t >> 6] = lsum;
    __syncthreads();
    const float Z = (reds[0] + reds[1]) + (reds[2] + reds[3]);
    const float inv = 1.0f / Z;
    #pragma unroll
    for (int c = 0; c < 4; ++c) {
        const int idx = c * 1024 + t * 4;
        ushort4 o;
        o.x = f2h_u(v[c].x * inv); o.y = f2h_u(v[c].y * inv);
        o.z = f2h_u(v[c].z * inv); o.w = f2h_u(v[c].w * inv);
        *reinterpret_cast<ushort4*>(&prow[idx]) = o;
    }
}

// ---------------------------------------------------------------------------
// MFMA GEMM (f16): C[M][N] = A_eff[M][K] * B_eff[K][N], B stored [N][K].
// AS/BS in {1,2}: operand given as hi (+lo). Terms: Ah*Bh [+ Ah*Bl] [+ Al*Bh].
// OUTMODE: 0 fp32, 1 f16, 2 f16 hi/lo pair. BK=32, 4 waves (2x2).
// blockIdx.z batches with element strides bsA/bsB/bsC. LDS k-slot XOR-swizzle
// via pre-swizzled global source (global_load_lds writes linearly; the two
// XORs cancel on the ds_read side — verified R5/R6).
// ---------------------------------------------------------------------------
template<int TR>
__device__ inline void stage_one(const ushort* __restrict__ g, int ld, int r0,
                                 int k0, ushort* ldsbase, int w, int l)
{
    constexpr int ISS = TR / 64;
    #pragma unroll
    for (int q = 0; q < ISS; ++q) {
        const int idx = (w * ISS + q) * 64 + l;           // 16B-slot id
        const int row = idx >> 2;
        const int gslot = (idx & 3) ^ ((idx >> 3) & 3);   // pre-swizzled source
        const ushort* src = g + (size_t)(r0 + row) * ld + k0 + gslot * 8;
        ushort* dst = ldsbase + (size_t)(w * ISS + q) * 512;  // wave-uniform
        __builtin_amdgcn_global_load_lds(
            (const __attribute__((address_space(1))) void*)src,
            (__attribute__((address_space(3))) void*)dst, 16, 0, 0);
    }
}

template<int BM, int BN, int AS, int BS, int OUTMODE>
__global__ __launch_bounds__(256, 2)
void mfma_gemm_k(const ushort* __restrict__ Ah, const ushort* __restrict__ Al,
                 const ushort* __restrict__ Bh, const ushort* __restrict__ Bl,
                 const float* __restrict__ bias,
                 float* __restrict__ Cf, ushort* __restrict__ Ch,
                 ushort* __restrict__ Cl,
                 int K, int lda, int ldb, int ldc,
                 long long bsA, long long bsB, long long bsC)
{
    constexpr int FM = BM / 32, FN = BN / 32;
    constexpr int AU = AS * BM * 32;            // A-panel ushorts
    constexpr int TILE_U = AU + BS * BN * 32;
    __shared__ __align__(16) ushort lds[2][TILE_U];

    const long long zb = blockIdx.z;
    Ah += zb * bsA; Bh += zb * bsB;
    if constexpr (AS == 2) Al += zb * bsA;
    if constexpr (BS == 2) Bl += zb * bsB;

    const int t = threadIdx.x;
    const int l = t & 63, w = t >> 6;
    const int lr = l & 15, ls = l >> 4;
    const int i0 = blockIdx.y * BM, j0 = blockIdx.x * BN;
    const int wr = (w >> 1) * (BM / 2), wc = (w & 1) * (BN / 2);
    const int swu = (ls ^ ((lr >> 1) & 3)) * 8; // swizzled k-slot (ushorts)

    f32x4 acc[FM][FN] = {};
    const int nk = K >> 5;

    auto stage = [&](int buf, int kt) {
        const int k0 = kt << 5;
        ushort* base = &lds[buf][0];
        stage_one<BM>(Ah, lda, i0, k0, base, w, l);
        if constexpr (AS == 2) stage_one<BM>(Al, lda, i0, k0, base + BM * 32, w, l);
        stage_one<BN>(Bh, ldb, j0, k0, base + AU, w, l);
        if constexpr (BS == 2) stage_one<BN>(Bl, ldb, j0, k0, base + AU + BN * 32, w, l);
    };

    stage(0, 0);
    for (int kt = 0; kt < nk; ++kt) {
        __syncthreads();                 // drains vmcnt: current buf staged
        const int buf = kt & 1;
        if (kt + 1 < nk) stage(buf ^ 1, kt + 1);
        const ushort* base = &lds[buf][0];

        short8 ah[FM], bh[FN];
        #pragma unroll
        for (int fi = 0; fi < FM; ++fi)
            ah[fi] = *reinterpret_cast<const short8*>(
                base + (wr + fi * 16 + lr) * 32 + swu);
        #pragma unroll
        for (int fj = 0; fj < FN; ++fj)
            bh[fj] = *reinterpret_cast<const short8*>(
                base + AU + (wc + fj * 16 + lr) * 32 + swu);

        #pragma unroll
        for (int fi = 0; fi < FM; ++fi)
            #pragma unroll
            for (int fj = 0; fj < FN; ++fj)
                acc[fi][fj] = __builtin_amdgcn_mfma_f32_16x16x32_f16(
                    ah[fi], bh[fj], acc[fi][fj], 0, 0, 0);

        if constexpr (BS == 2) {
            short8 bl[FN];
            #pragma unroll
            for (int fj = 0; fj < FN; ++fj)
                bl[fj] = *reinterpret_cast<const short8*>(
                    base + AU + BN * 32 + (wc + fj * 16 + lr) * 32 + swu);
            #pragma unroll
            for (int fi = 0; fi < FM; ++fi)
                #pragma unroll
                for (int fj = 0; fj < FN; ++fj)
                    acc[fi][fj] = __builtin_amdgcn_mfma_f32_16x16x32_f16(
                        ah[fi], bl[fj], acc[fi][fj], 0, 0, 0);
        }
        if constexpr (AS == 2) {
            short8 al[FM];
            #pragma unroll
            for (int fi = 0; fi < FM; ++fi)
                al[fi] = *reinterpret_cast<const short8*>(
                    base + BM * 32 + (wr + fi * 16 + lr) * 32 + swu);
            #pragma unroll
            for (int fi = 0; fi < FM; ++fi)
                #pragma unroll
                for (int fj = 0; fj < FN; ++fj)
                    acc[fi][fj] = __builtin_amdgcn_mfma_f32_16x16x32_f16(
                        al[fi], bh[fj], acc[fi][fj], 0, 0, 0);
        }
    }

    // epilogue: C/D layout col=lane&15, row=(lane>>4)*4+reg
    #pragma unroll
    for (int fj = 0; fj < FN; ++fj) {
        const int gc = j0 + wc + fj * 16 + lr;
        const float bv = bias ? bias[gc] : 0.0f;
        #pragma unroll
        for (int fi = 0; fi < FM; ++fi) {
            const int gr = i0 + wr + fi * 16 + ls * 4;
            #pragma unroll
            for (int r = 0; r < 4; ++r) {
                const float v = acc[fi][fj][r] + bv;
                const size_t o = zb * bsC + (size_t)(gr + r) * ldc + gc;
                if constexpr (OUTMODE == 0) {
                    Cf[o] = v;
                } else if constexpr (OUTMODE == 1) {
                    Ch[o] = f2h_u(v);
                } else {
                    ushort h, lo2; split2h(v, h, lo2);
                    Ch[o] = h;
                    Cl[o] = lo2;
                }
            }
        }
    }
}

// ---------------------------------------------------------------------------
extern "C" void kernel_launch(void* const* d_in, const int* in_sizes, int n_in,
                              void* d_out, int out_size, void* d_ws, size_t ws_size,
                              hipStream_t stream)
{
    (void)in_sizes; (void)n_in; (void)out_size;
    const int NB = 8, LQ = 1024, LI = 4096, D = 1024;
    const long long sQD = (long long)LQ * D;   // 1M
    const long long sID = (long long)LI * D;   // 4M
    const long long sQI = (long long)LQ * LI;  // 4M

    const float* query = (const float*)d_in[0];
    const float* input = (const float*)d_in[1];
    const int* mask = (const int*)d_in[2];   // bool -> int32 on device
    const float* Wq = (const float*)d_in[3];
    const float* bq = (const float*)d_in[4];
    const float* Wk = (const float*)d_in[5];
    /* d_in[6] = bk: cancels in softmax */
    const float* Wo = (const float*)d_in[7];
    const float* bo = (const float*)d_in[8];
    float* out = (float*)d_out;

    dim3 blk(256);

    char* p = (char*)d_ws;
    auto alloc = [&](size_t bytes) {
        char* r = p; p += (bytes + 255) & ~(size_t)255; return r;
    };
    // head buffers
    ushort* qh   = (ushort*)alloc((size_t)NB * sQD * 2);  // query f16
    ushort* WqTh = (ushort*)alloc((size_t)D * D * 2);
    ushort* WqTl = (ushort*)alloc((size_t)D * D * 2);
    ushort* WkTh = (ushort*)alloc((size_t)D * D * 2);
    ushort* WkTl = (ushort*)alloc((size_t)D * D * 2);
    ushort* WTh  = (ushort*)alloc((size_t)D * D * 2);     // W'^T hi/lo
    ushort* WTl  = (ushort*)alloc((size_t)D * D * 2);
    float*  bp   = (float*) alloc((size_t)D * 4);
    ushort* Qh   = (ushort*)alloc((size_t)NB * sQD * 2);  // Q'' f16 (single)
    ushort* Ob   = (ushort*)alloc((size_t)NB * sQD * 2);  // O f16
    ushort* Wob  = (ushort*)alloc((size_t)D * D * 2);     // Wo f16
    char* tail = p;

    // full-batch tail
    ushort* inh = (ushort*)alloc((size_t)NB * sID * 2);
    ushort* inl = (ushort*)alloc((size_t)NB * sID * 2);
    ushort* VT  = (ushort*)alloc((size_t)NB * sID * 2);
    float*  S   = (float*) alloc((size_t)NB * sQI * 4);
    ushort* Pb  = (ushort*)alloc((size_t)NB * sQI * 2);
    const bool full = (size_t)(p - (char*)d_ws) <= ws_size;
    if (!full) {
        p = tail;
        inh = (ushort*)alloc((size_t)sID * 2);
        inl = (ushort*)alloc((size_t)sID * 2);
        VT  = (ushort*)alloc((size_t)sID * 2);
        S   = (float*) alloc((size_t)sQI * 4);
        Pb  = (ushort*)alloc((size_t)sQI * 2);
    }

    // ---- head ----
    trans_split_k<<<dim3(32, 32), blk, 0, stream>>>(Wq, WqTh, WqTl, D, D);
    trans_split_k<<<dim3(32, 32), blk, 0, stream>>>(Wk, WkTh, WkTl, D, D);
    bias_proj_k<<<dim3(4), blk, 0, stream>>>(bq, Wk, bp);
    // W'^T[j][k] = sum_d Wk[d][j]*Wq[d][k]  (A=WkT, B=WqT; split-2 both sides)
    mfma_gemm_k<64, 64, 2, 2, 2><<<dim3(16, 16, 1), blk, 0, stream>>>(
        WkTh, WkTl, WqTh, WqTl, nullptr, nullptr, WTh, WTl, D, D, D, D, 0, 0, 0);
    split_k<<<dim3(2048), blk, 0, stream>>>(query, qh, nullptr, NB * (int)sQD / 4);
    split_k<<<dim3(1024), blk, 0, stream>>>(Wo, Wob, nullptr, D * D / 4);
    // Q'' = query @ W' + b'  (A single, B hi/lo -> 2 MFMAs; f16 out)
    mfma_gemm_k<128, 128, 1, 2, 1><<<dim3(D / 128, NB * LQ / 128, 1), blk, 0, stream>>>(
        qh, nullptr, WTh, WTl, bp, nullptr, Qh, nullptr, D, D, D, D, 0, 0, 0);

    if (full) {
        prep_input_k<<<dim3(D / 32, LI / 32, NB), blk, 0, stream>>>(
            input, inh, inl, VT, LI, D, sID);
        // S = Q'' @ input^T  (A single, B hi/lo -> 2 MFMAs; fp32 out)
        mfma_gemm_k<128, 128, 1, 2, 0><<<dim3(LI / 128, LQ / 128, NB), blk, 0, stream>>>(
            Qh, nullptr, inh, inl, nullptr, S, nullptr, nullptr,
            D, D, D, LI, sQD, sID, sQI);
        softmax_f16_k<<<dim3(LQ, NB), blk, 0, stream>>>(S, mask, Pb);
        // O = P @ V  (plain f16)
        mfma_gemm_k<128, 128, 1, 1, 1><<<dim3(D / 128, LQ / 128, NB), blk, 0, stream>>>(
            Pb, nullptr, VT, nullptr, nullptr, nullptr, Ob, nullptr,
            LI, LI, LI, D, sQI, sID, sQD);
    } else {
        for (int b = 0; b < NB; ++b) {
            const float* in_b = input + (size_t)b * sID;
            prep_input_k<<<dim3(D / 32, LI / 32, 1), blk, 0, stream>>>(
                in_b, inh, inl, VT, LI, D, 0);
            mfma_gemm_k<128, 128, 1, 2, 0><<<dim3(LI / 128, LQ / 128, 1), blk, 0, stream>>>(
                Qh + (size_t)b * sQD, nullptr, inh, inl, nullptr, S, nullptr, nullptr,
                D, D, D, LI, 0, 0, 0);
            softmax_f16_k<<<dim3(LQ, 1), blk, 0, stream>>>(S, mask + (size_t)b * LI, Pb);
            mfma_gemm_k<128, 128, 1, 1, 1><<<dim3(D / 128, LQ / 128, 1), blk, 0, stream>>>(
                Pb, nullptr, VT, nullptr, nullptr, nullptr,
                Ob + (size_t)b * sQD, nullptr, LI, LI, LI, D, 0, 0, 0);
        }
    }
    // out = O @ Wo^T + bo (fp32 out)
    mfma_gemm_k<128, 128, 1, 1, 0><<<dim3(D / 128, NB * LQ / 128, 1), blk, 0, stream>>>(
        Ob, nullptr, Wob, nullptr, bo, out, nullptr, nullptr, D, D, D, D, 0, 0, 0);
}